// Round 9
// baseline (1271.252 us; speedup 1.0000x reference)
//
#include <hip/hip_runtime.h>

#define T_STEPS 512
#define HS 20        // hidden size
#define F0 10        // input features (layer 0)
#define NBAT 3       // batches per lane (per 20-lane group)
#define BPB (3 * NBAT)                    // 9 batches per block
#define NB_TOT 4096
#define NBLK ((NB_TOT + BPB - 1) / BPB)   // 456

__device__ __forceinline__ float sigmoid_fast(float v) {
    return __fdividef(1.f, 1.f + __expf(-v));
}
__device__ __forceinline__ float tanh_fast(float v) {
    return 1.f - __fdividef(2.f, __expf(2.f * v) + 1.f);
}
#define PIN(v) asm volatile("" : "+v"(v))

// Layer-split skew-1 pipeline (R7-verified), 9 batches/block (3 per lane):
//   wave0: layer0 step t for 9 batches; wave1: layer1 step t-1.
//   456 blocks = 912 waves -> ~1 wave/SIMD UNIFORM (no 2-wave makespan SIMDs).
//   Weights pinned (live in AGPRs at (128,2) - never scratch); inner loops are
//   weight-outer/batch-inner so each unique weight = 1 accvgpr_read + 3 fmac.
__global__ __launch_bounds__(128, 2)
void lstm2_fc_kernel(const float* __restrict__ x,
                     const float* __restrict__ wih0, const float* __restrict__ whh0,
                     const float* __restrict__ bih0, const float* __restrict__ bhh0,
                     const float* __restrict__ wih1, const float* __restrict__ whh1,
                     const float* __restrict__ bih1, const float* __restrict__ bhh1,
                     const float* __restrict__ wfc,  const float* __restrict__ bfc,
                     float* __restrict__ out)
{
    const int tid  = threadIdx.x;
    const int wid  = tid >> 6;
    const int lane = tid & 63;
    const int g    = (lane / HS) % 3;   // lanes 60..63 shadow group 0 (benign dups)
    const int u    = lane % HS;

    int  bgr[NBAT], bg[NBAT];
    bool ok[NBAT];
    #pragma unroll
    for (int b = 0; b < NBAT; ++b) {
        bgr[b] = blockIdx.x * BPB + g + 3 * b;
        ok[b]  = (bgr[b] < NB_TOT);
        bg[b]  = ok[b] ? bgr[b] : (NB_TOT - 1);   // clamp reads
    }

    __shared__ float s_h0[2][BPB][HS];   // double buffer: wave0 -> wave1
    __shared__ float s_h1[BPB][HS];      // wave1-private recurrence state

    for (int i = tid; i < 2 * BPB * HS; i += 128) (&s_h0[0][0][0])[i] = 0.f;
    for (int i = tid; i < BPB * HS; i += 128)     (&s_h1[0][0])[i]    = 0.f;

    // ---- per-lane weights, SHARED storage between the two wave roles ----
    // wave0: w[q][0..9] = wih0 row, w[q][10..29] = whh0 row
    // wave1: w[q][0..19] = wih1 row, w[q][20..39] = whh1 row
    float w[4][2 * HS], bias[4];
    if (wid == 0) {
        #pragma unroll
        for (int q = 0; q < 4; ++q) {
            const int row = q * HS + u;
            #pragma unroll
            for (int f = 0; f < F0; ++f) { w[q][f] = wih0[row * F0 + f]; PIN(w[q][f]); }
            #pragma unroll
            for (int j = 0; j < HS; ++j) { w[q][F0 + j] = whh0[row * HS + j]; PIN(w[q][F0 + j]); }
            bias[q] = bih0[row] + bhh0[row]; PIN(bias[q]);
        }
    } else {
        #pragma unroll
        for (int q = 0; q < 4; ++q) {
            const int row = q * HS + u;
            #pragma unroll
            for (int j = 0; j < HS; ++j) { w[q][j]      = wih1[row * HS + j]; PIN(w[q][j]); }
            #pragma unroll
            for (int j = 0; j < HS; ++j) { w[q][HS + j] = whh1[row * HS + j]; PIN(w[q][HS + j]); }
            bias[q] = bih1[row] + bhh1[row]; PIN(bias[q]);
        }
    }

    float c[NBAT];
    #pragma unroll
    for (int b = 0; b < NBAT; ++b) c[b] = 0.f;

    const float* xb[NBAT];
    #pragma unroll
    for (int b = 0; b < NBAT; ++b) xb[b] = x + (size_t)bg[b] * (T_STEPS * F0);

    __syncthreads();

    for (int t = 0; t <= T_STEPS; ++t) {
        if (wid == 0) {
            if (t < T_STEPS) {
                // x(t) for 3 batches, issued first (latency covered by h-FMAs)
                float xr[NBAT][F0];
                #pragma unroll
                for (int b = 0; b < NBAT; ++b) {
                    const float2* p = (const float2*)(xb[b] + t * F0);
                    #pragma unroll
                    for (int f = 0; f < F0 / 2; ++f) {
                        float2 v = p[f];
                        xr[b][2*f] = v.x; xr[b][2*f+1] = v.y;
                    }
                }
                float acc[NBAT][4];
                #pragma unroll
                for (int b = 0; b < NBAT; ++b) {
                    #pragma unroll
                    for (int q = 0; q < 4; ++q) acc[b][q] = bias[q];
                }
                const int pb = (t + 1) & 1;              // h0(t-1) buffer
                #pragma unroll
                for (int q4 = 0; q4 < HS / 4; ++q4) {
                    float e[NBAT][4];
                    #pragma unroll
                    for (int b = 0; b < NBAT; ++b) {
                        const float4 h4 = *(const float4*)(&s_h0[pb][g + 3 * b][4 * q4]);
                        e[b][0] = h4.x; e[b][1] = h4.y; e[b][2] = h4.z; e[b][3] = h4.w;
                    }
                    #pragma unroll
                    for (int s = 0; s < 4; ++s) {
                        const int k = F0 + 4 * q4 + s;
                        #pragma unroll
                        for (int q = 0; q < 4; ++q) {
                            const float wk = w[q][k];    // 1 read, NBAT uses
                            #pragma unroll
                            for (int b = 0; b < NBAT; ++b)
                                acc[b][q] = fmaf(e[b][s], wk, acc[b][q]);
                        }
                    }
                }
                #pragma unroll
                for (int f = 0; f < F0; ++f) {
                    #pragma unroll
                    for (int q = 0; q < 4; ++q) {
                        const float wk = w[q][f];
                        #pragma unroll
                        for (int b = 0; b < NBAT; ++b)
                            acc[b][q] = fmaf(xr[b][f], wk, acc[b][q]);
                    }
                }
                #pragma unroll
                for (int b = 0; b < NBAT; ++b) {
                    const float ii = sigmoid_fast(acc[b][0]);
                    const float ff = sigmoid_fast(acc[b][1]);
                    const float gg = tanh_fast(acc[b][2]);
                    const float oo = sigmoid_fast(acc[b][3]);
                    c[b] = ff * c[b] + ii * gg;
                    s_h0[t & 1][g + 3 * b][u] = oo * tanh_fast(c[b]);
                }
            }
        } else {
            if (t >= 1) {
                // layer1 computes step s = t-1
                float acc[NBAT][4];
                #pragma unroll
                for (int b = 0; b < NBAT; ++b) {
                    #pragma unroll
                    for (int q = 0; q < 4; ++q) acc[b][q] = bias[q];
                }
                const int pb = (t - 1) & 1;              // h0(t-1) buffer
                #pragma unroll
                for (int q4 = 0; q4 < HS / 4; ++q4) {
                    float e[NBAT][4];
                    #pragma unroll
                    for (int b = 0; b < NBAT; ++b) {
                        const float4 h4 = *(const float4*)(&s_h0[pb][g + 3 * b][4 * q4]);
                        e[b][0] = h4.x; e[b][1] = h4.y; e[b][2] = h4.z; e[b][3] = h4.w;
                    }
                    #pragma unroll
                    for (int s = 0; s < 4; ++s) {
                        const int k = 4 * q4 + s;
                        #pragma unroll
                        for (int q = 0; q < 4; ++q) {
                            const float wk = w[q][k];
                            #pragma unroll
                            for (int b = 0; b < NBAT; ++b)
                                acc[b][q] = fmaf(e[b][s], wk, acc[b][q]);
                        }
                    }
                }
                #pragma unroll
                for (int q4 = 0; q4 < HS / 4; ++q4) {
                    float e[NBAT][4];
                    #pragma unroll
                    for (int b = 0; b < NBAT; ++b) {
                        const float4 h4 = *(const float4*)(&s_h1[g + 3 * b][4 * q4]);
                        e[b][0] = h4.x; e[b][1] = h4.y; e[b][2] = h4.z; e[b][3] = h4.w;
                    }
                    #pragma unroll
                    for (int s = 0; s < 4; ++s) {
                        const int k = HS + 4 * q4 + s;
                        #pragma unroll
                        for (int q = 0; q < 4; ++q) {
                            const float wk = w[q][k];
                            #pragma unroll
                            for (int b = 0; b < NBAT; ++b)
                                acc[b][q] = fmaf(e[b][s], wk, acc[b][q]);
                        }
                    }
                }
                float hnew[NBAT];
                #pragma unroll
                for (int b = 0; b < NBAT; ++b) {
                    const float ii = sigmoid_fast(acc[b][0]);
                    const float ff = sigmoid_fast(acc[b][1]);
                    const float gg = tanh_fast(acc[b][2]);
                    const float oo = sigmoid_fast(acc[b][3]);
                    c[b] = ff * c[b] + ii * gg;
                    hnew[b] = oo * tanh_fast(c[b]);
                }
                __builtin_amdgcn_wave_barrier();   // h1(s-1) reads precede writes
                #pragma unroll
                for (int b = 0; b < NBAT; ++b) s_h1[g + 3 * b][u] = hnew[b];
            }
        }
        __syncthreads();   // publish s_h0[t&1]; WAR-protect buffer reuse
    }

    // ---- final FC on h1(T-1) ----
    if (wid == 1 && lane < 60 && u == 0) {
        #pragma unroll
        for (int b = 0; b < NBAT; ++b) {
            float o = bfc[0];
            #pragma unroll
            for (int j = 0; j < HS; ++j) o = fmaf(s_h1[g + 3 * b][j], wfc[j], o);
            if (ok[b]) out[bgr[b]] = o;
        }
    }
}

extern "C" void kernel_launch(void* const* d_in, const int* in_sizes, int n_in,
                              void* d_out, int out_size, void* d_ws, size_t ws_size,
                              hipStream_t stream) {
    const float* x    = (const float*)d_in[0];
    const float* wih0 = (const float*)d_in[1];
    const float* whh0 = (const float*)d_in[2];
    const float* bih0 = (const float*)d_in[3];
    const float* bhh0 = (const float*)d_in[4];
    const float* wih1 = (const float*)d_in[5];
    const float* whh1 = (const float*)d_in[6];
    const float* bih1 = (const float*)d_in[7];
    const float* bhh1 = (const float*)d_in[8];
    const float* wfc  = (const float*)d_in[9];
    const float* bfc  = (const float*)d_in[10];
    float* out = (float*)d_out;

    dim3 grid(NBLK), block(128);
    hipLaunchKernelGGL(lstm2_fc_kernel, grid, block, 0, stream,
                       x, wih0, whh0, bih0, bhh0,
                       wih1, whh1, bih1, bhh1, wfc, bfc, out);
}